// Round 3
// baseline (3817.598 us; speedup 1.0000x reference)
//
#include <hip/hip_runtime.h>

typedef __bf16 bf16;
typedef __attribute__((ext_vector_type(8))) __bf16 bf16x8;
typedef __attribute__((ext_vector_type(4))) float f32x4;

#define TOKENS 3136
#define CC 768
#define KVC 1536
#define S196 196
#define M_ROWS 25088   // 16*8*196
#define BATCH 16

__device__ __forceinline__ float bf2f(bf16 x) { return (float)x; }
__device__ __forceinline__ bf16 f2bf(float x) { return (bf16)x; }

__device__ __forceinline__ float gelu_exact(float x) {
    return 0.5f * x * (1.0f + erff(x * 0.70710678118654752f));
}

// ---------------------------------------------------------------------------
// Weight transpose + bf16 convert: Wt[n][k] = W[k][n]   (fp32 input)
// ---------------------------------------------------------------------------
__global__ __launch_bounds__(256)
void transpose_w(const float* __restrict__ W, bf16* __restrict__ Wt, int K, int N)
{
    __shared__ float tle[32][33];
    int k0 = blockIdx.x * 32, n0 = blockIdx.y * 32;
    int tx = threadIdx.x & 31, ty = threadIdx.x >> 5;   // 8 rows of 32
    for (int r = ty; r < 32; r += 8)
        tle[r][tx] = W[(long)(k0 + r) * N + n0 + tx];
    __syncthreads();
    for (int r = ty; r < 32; r += 8)
        Wt[(long)(n0 + r) * K + k0 + tx] = f2bf(tle[tx][r]);
}

// ---------------------------------------------------------------------------
// Bias convert (fp32 -> bf16) into packed ws array
// ---------------------------------------------------------------------------
__global__ __launch_bounds__(256)
void conv_bias(const float* b0, const float* b1, const float* b2,
               const float* b3, const float* b4, const float* b5,
               bf16* __restrict__ dst)
{
    const float* srcs[6] = {b0, b1, b2, b3, b4, b5};
    const int sizes[6]   = {768, 1536, 768, 1536, 768, 768};
    const int offs[6]    = {0, 768, 2304, 3072, 4608, 5376};
    int which = blockIdx.x;
    const float* s = srcs[which];
    int n = sizes[which];
    bf16* d = dst + offs[which];
    for (int i = threadIdx.x; i < n; i += 256)
        d[i] = f2bf(s[i]);
}

// ---------------------------------------------------------------------------
// Reorder x_in (b, nt, nh, nw, t, c) fp32 -> bf16 x_a / x_d rows
// tt = nt*4+t ; even tt -> x_a, odd -> x_d ; j = tt>>1 ; s = nh*14+nw
// ---------------------------------------------------------------------------
__global__ __launch_bounds__(256)
void reorder_split(const float* __restrict__ x_in, bf16* __restrict__ xa,
                   bf16* __restrict__ xd)
{
    long idx = (long)blockIdx.x * 256 + threadIdx.x;
    const long total = (long)BATCH * 16 * S196 * 96;   // 96 chunks of 8 per row
    if (idx >= total) return;
    int  c8  = (int)(idx % 96) * 8;
    long row = idx / 96;
    int  s   = (int)(row % S196);
    long r2  = row / S196;
    int  tt  = (int)(r2 & 15);
    int  b   = (int)(r2 >> 4);
    int  nt  = tt >> 2, t = tt & 3;
    int  nh  = s / 14,  nw = s % 14;
    long src  = ((long)b * TOKENS + ((nt * 14 + nh) * 14 + nw) * 4 + t) * CC + c8;
    bf16* dst = (tt & 1) ? xd : xa;
    long doff = ((long)(b * 8 + (tt >> 1)) * S196 + s) * CC + c8;
    const float* sp = x_in + src;
    f32x4 a = *(const f32x4*)sp;
    f32x4 c = *(const f32x4*)(sp + 4);
    bf16x8 v;
    v[0] = f2bf(a[0]); v[1] = f2bf(a[1]); v[2] = f2bf(a[2]); v[3] = f2bf(a[3]);
    v[4] = f2bf(c[0]); v[5] = f2bf(c[1]); v[6] = f2bf(c[2]); v[7] = f2bf(c[3]);
    *(bf16x8*)(dst + doff) = v;
}

// ---------------------------------------------------------------------------
// GEMM: C = A(MxK) @ Bt(NxK)^T + bias, bf16 in/out, fp32 accum via MFMA.
// 128x128 tile, 4 waves (2x2), each wave 64x64 = 4x4 mfma_f32_16x16x32_bf16.
// EPI: 0 -> C = x ; 1 -> C = res - gelu(x) ; 2 -> C = res + gelu(x)
// ---------------------------------------------------------------------------
template<int EPI>
__global__ __launch_bounds__(256)
void gemm_bt(const bf16* __restrict__ A, const bf16* __restrict__ Bt,
             const bf16* __restrict__ bias, const bf16* __restrict__ res,
             bf16* __restrict__ C, int N, int K)
{
    constexpr int BM = 128, BN = 128, BK = 32, LSTR = 40;  // +8 pad
    __shared__ bf16 sA[BM * LSTR];
    __shared__ bf16 sB[BN * LSTR];
    const int tid  = threadIdx.x;
    const int lane = tid & 63, wave = tid >> 6;
    const int wm   = wave >> 1, wn = wave & 1;
    const int quad = lane >> 4, l16 = lane & 15;
    const long m0 = (long)blockIdx.x * BM;
    const long n0 = (long)blockIdx.y * BN;

    f32x4 acc[4][4] = {};

    for (int kt = 0; kt < K; kt += BK) {
        if (kt) __syncthreads();
        #pragma unroll
        for (int c = 0; c < 2; ++c) {
            int ci = tid + c * 256;          // 512 chunks of 16B per tile
            int r  = ci >> 2, kc = ci & 3;
            bf16x8 av = *(const bf16x8*)(A  + (m0 + r) * K + kt + kc * 8);
            bf16x8 bv = *(const bf16x8*)(Bt + (n0 + r) * K + kt + kc * 8);
            *(bf16x8*)(sA + r * LSTR + kc * 8) = av;
            *(bf16x8*)(sB + r * LSTR + kc * 8) = bv;
        }
        __syncthreads();

        bf16x8 af[4], bfr[4];
        #pragma unroll
        for (int mi = 0; mi < 4; ++mi)
            af[mi] = *(const bf16x8*)(sA + (wm * 64 + mi * 16 + l16) * LSTR + quad * 8);
        #pragma unroll
        for (int ni = 0; ni < 4; ++ni)
            bfr[ni] = *(const bf16x8*)(sB + (wn * 64 + ni * 16 + l16) * LSTR + quad * 8);
        #pragma unroll
        for (int mi = 0; mi < 4; ++mi)
            #pragma unroll
            for (int ni = 0; ni < 4; ++ni)
                acc[mi][ni] = __builtin_amdgcn_mfma_f32_16x16x32_bf16(af[mi], bfr[ni], acc[mi][ni], 0, 0, 0);
    }

    // Epilogue. D layout: col = lane&15, row = quad*4 + r  (HW-verified m89)
    #pragma unroll
    for (int mi = 0; mi < 4; ++mi) {
        #pragma unroll
        for (int ni = 0; ni < 4; ++ni) {
            int mg = (int)m0 + wm * 64 + mi * 16 + quad * 4;
            int ng = (int)n0 + wn * 64 + ni * 16 + l16;
            float bn = bf2f(bias[ng]);
            #pragma unroll
            for (int r = 0; r < 4; ++r) {
                float x = acc[mi][ni][r] + bn;
                long off = (long)(mg + r) * N + ng;
                if (EPI == 0)      C[off] = f2bf(x);
                else if (EPI == 1) C[off] = f2bf(bf2f(res[off]) - gelu_exact(x));
                else               C[off] = f2bf(bf2f(res[off]) + gelu_exact(x));
            }
        }
    }
}

// ---------------------------------------------------------------------------
// Attention (scalar baseline): one block per (head, b*8+j).
// q, k_t in LDS; row-per-wave; shuffle softmax; v streamed via L1.
// ---------------------------------------------------------------------------
__global__ __launch_bounds__(256)
void attn(const bf16* __restrict__ Q, const bf16* __restrict__ KV, bf16* __restrict__ O)
{
    const int h  = blockIdx.x;   // 12
    const int bj = blockIdx.y;   // 128
    __shared__ bf16 q_s[S196 * 64];     // [token][d]
    __shared__ bf16 k_t[64][256];       // [d][token], padded to 256
    const int tid = threadIdx.x, lane = tid & 63, wave = tid >> 6;

    const bf16* qg = Q  + (long)bj * S196 * CC  + h * 64;
    const bf16* kg = KV + (long)bj * S196 * KVC + h * 64;
    const bf16* vg = kg + CC;   // v at column 768 + h*64

    for (int idx = tid; idx < 64 * 60; idx += 256) {
        int d = idx / 60, jp = 196 + idx % 60;
        k_t[d][jp] = f2bf(0.f);
    }
    for (int idx = tid; idx < S196 * 64; idx += 256) {
        int j = idx >> 6, d = idx & 63;
        q_s[idx]  = qg[(long)j * CC  + d];
        k_t[d][j] = kg[(long)j * KVC + d];
    }
    __syncthreads();

    const float SC = 0.125f;
    for (int i = wave; i < S196; i += 4) {    // 49 rows per wave
        float s0 = 0.f, s1 = 0.f, s2 = 0.f, s3 = 0.f;
        for (int d = 0; d < 64; ++d) {
            float qd = bf2f(q_s[i * 64 + d]);
            s0 += qd * bf2f(k_t[d][lane]);
            s1 += qd * bf2f(k_t[d][64  + lane]);
            s2 += qd * bf2f(k_t[d][128 + lane]);
            s3 += qd * bf2f(k_t[d][192 + lane]);
        }
        s0 *= SC; s1 *= SC; s2 *= SC;
        s3 = (lane < 4) ? s3 * SC : -1e30f;

        float m = fmaxf(fmaxf(s0, s1), fmaxf(s2, s3));
        #pragma unroll
        for (int off = 32; off; off >>= 1) m = fmaxf(m, __shfl_xor(m, off, 64));

        float e0 = expf(s0 - m), e1 = expf(s1 - m), e2 = expf(s2 - m);
        float e3 = (lane < 4) ? expf(s3 - m) : 0.f;
        float sum = e0 + e1 + e2 + e3;
        #pragma unroll
        for (int off = 32; off; off >>= 1) sum += __shfl_xor(sum, off, 64);
        float inv = 1.0f / sum;

        float e[4] = {e0, e1, e2, e3};
        float o = 0.f;                      // lane = output dim d
        #pragma unroll
        for (int jj = 0; jj < 4; ++jj) {
            const int jmax = (jj == 3) ? 4 : 64;
            for (int src = 0; src < jmax; ++src) {
                float p = __shfl(e[jj], src, 64);
                o += p * bf2f(vg[(long)(jj * 64 + src) * KVC + lane]);
            }
        }
        O[((long)bj * S196 + i) * CC + h * 64 + lane] = f2bf(o * inv);
    }
}

// ---------------------------------------------------------------------------
// Outputs (fp32): pool_a[b,j,s] = mean_c((x_e+x_o)/2) - mean_c(x_a_new)
//                 x_d_out[b,j,s] = mean_c(x_d_new)
// One block per (b*8+j)*196+s; wave0/1: x_in rows (fp32 exact); wave2: xa; wave3: xd
// ---------------------------------------------------------------------------
__global__ __launch_bounds__(256)
void out_reduce(const float* __restrict__ x_in, const bf16* __restrict__ xa,
                const bf16* __restrict__ xd, float* __restrict__ out)
{
    int id = blockIdx.x;
    int s  = id % S196;
    int bj = id / S196;
    int j  = bj & 7, b = bj >> 3;
    int tid = threadIdx.x, lane = tid & 63, wave = tid >> 6;
    int nh = s / 14, nw = s % 14;

    float sum = 0.f;
    if (wave < 2) {
        int tt = 2 * j + wave;
        int nt = tt >> 2, t = tt & 3;
        const float* p = x_in + ((long)b * TOKENS + ((nt * 14 + nh) * 14 + nw) * 4 + t) * CC;
        for (int c = lane; c < CC; c += 64) sum += p[c];
    } else {
        const bf16* p = (wave == 2 ? xa : xd) + (long)id * CC;
        for (int c = lane; c < CC; c += 64) sum += bf2f(p[c]);
    }
    #pragma unroll
    for (int off = 32; off; off >>= 1) sum += __shfl_xor(sum, off, 64);

    __shared__ float r4[4];
    if (lane == 0) r4[wave] = sum;
    __syncthreads();
    if (tid == 0) {
        const float invC = 1.0f / 768.0f;
        out[id]          = (r4[0] + r4[1]) * 0.5f * invC - r4[2] * invC;
        out[M_ROWS + id] = r4[3] * invC;
    }
}

// ---------------------------------------------------------------------------
extern "C" void kernel_launch(void* const* d_in, const int* in_sizes, int n_in,
                              void* d_out, int out_size, void* d_ws, size_t ws_size,
                              hipStream_t stream)
{
    const float* x_in  = (const float*)d_in[0];
    const float* Wq_d  = (const float*)d_in[1];
    const float* bq_d  = (const float*)d_in[2];
    const float* Wkv_a = (const float*)d_in[3];
    const float* bkv_a = (const float*)d_in[4];
    const float* Wq_a  = (const float*)d_in[5];
    const float* bq_a  = (const float*)d_in[6];
    const float* Wkv_d = (const float*)d_in[7];
    const float* bkv_d = (const float*)d_in[8];
    const float* Wp_d  = (const float*)d_in[9];
    const float* bp_d  = (const float*)d_in[10];
    const float* Wp_a  = (const float*)d_in[11];
    const float* bp_a  = (const float*)d_in[12];
    float* out = (float*)d_out;

    char* w = (char*)d_ws;
    auto alloc = [&](size_t elems) {
        bf16* p = (bf16*)w;
        w += ((elems * 2 + 255) / 256) * 256;
        return p;
    };
    bf16* biasAll = alloc(6144);
    bf16* WtQd = alloc((size_t)768 * 768);
    bf16* WtKa = alloc((size_t)1536 * 768);
    bf16* WtQa = alloc((size_t)768 * 768);
    bf16* WtKd = alloc((size_t)1536 * 768);
    bf16* WtPd = alloc((size_t)768 * 768);
    bf16* WtPa = alloc((size_t)768 * 768);
    bf16* xa   = alloc((size_t)M_ROWS * 768);
    bf16* xd   = alloc((size_t)M_ROWS * 768);
    bf16* Qb   = alloc((size_t)M_ROWS * 768);
    bf16* KVb  = alloc((size_t)M_ROWS * 1536);
    bf16* Ob   = alloc((size_t)M_ROWS * 768);

    dim3 blk(256);
    transpose_w<<<dim3(24, 24), blk, 0, stream>>>(Wq_d,  WtQd, 768, 768);
    transpose_w<<<dim3(24, 48), blk, 0, stream>>>(Wkv_a, WtKa, 768, 1536);
    transpose_w<<<dim3(24, 24), blk, 0, stream>>>(Wq_a,  WtQa, 768, 768);
    transpose_w<<<dim3(24, 48), blk, 0, stream>>>(Wkv_d, WtKd, 768, 1536);
    transpose_w<<<dim3(24, 24), blk, 0, stream>>>(Wp_d,  WtPd, 768, 768);
    transpose_w<<<dim3(24, 24), blk, 0, stream>>>(Wp_a,  WtPa, 768, 768);
    conv_bias<<<dim3(6), blk, 0, stream>>>(bq_d, bkv_a, bq_a, bkv_d, bp_d, bp_a, biasAll);

    long total_chunks = (long)BATCH * 16 * S196 * 96;
    int  rblocks = (int)((total_chunks + 255) / 256);
    reorder_split<<<rblocks, blk, 0, stream>>>(x_in, xa, xd);

    const bf16* Bq_d  = biasAll;
    const bf16* Bkv_a = biasAll + 768;
    const bf16* Bq_a  = biasAll + 2304;
    const bf16* Bkv_d = biasAll + 3072;
    const bf16* Bp_d  = biasAll + 4608;
    const bf16* Bp_a  = biasAll + 5376;

    dim3 g768(196, 6), g1536(196, 12);

    // Phase 1: _d = attn(q=x_d, kv=x_a); x_d -= gelu(_d @ Wp_d + bp_d)
    gemm_bt<0><<<g768,  blk, 0, stream>>>(xd, WtQd, Bq_d,  nullptr, Qb,  768,  768);
    gemm_bt<0><<<g1536, blk, 0, stream>>>(xa, WtKa, Bkv_a, nullptr, KVb, 1536, 768);
    attn<<<dim3(12, 128), blk, 0, stream>>>(Qb, KVb, Ob);
    gemm_bt<1><<<g768,  blk, 0, stream>>>(Ob, WtPd, Bp_d,  xd,      xd,  768,  768);

    // Phase 2: _a = attn(q=x_a, kv=x_d_new); x_a += gelu(_a @ Wp_a + bp_a)
    gemm_bt<0><<<g768,  blk, 0, stream>>>(xa, WtQa, Bq_a,  nullptr, Qb,  768,  768);
    gemm_bt<0><<<g1536, blk, 0, stream>>>(xd, WtKd, Bkv_d, nullptr, KVb, 1536, 768);
    attn<<<dim3(12, 128), blk, 0, stream>>>(Qb, KVb, Ob);
    gemm_bt<2><<<g768,  blk, 0, stream>>>(Ob, WtPa, Bp_a,  xa,      xa,  768,  768);

    out_reduce<<<M_ROWS, blk, 0, stream>>>(x_in, xa, xd, out);
}

// Round 4
// 1129.845 us; speedup vs baseline: 3.3789x; 3.3789x over previous
//
#include <hip/hip_runtime.h>

typedef __bf16 bf16;
typedef __attribute__((ext_vector_type(8))) __bf16 bf16x8;
typedef __attribute__((ext_vector_type(4))) __bf16 bf16x4;
typedef __attribute__((ext_vector_type(2))) __bf16 bf16x2;
typedef __attribute__((ext_vector_type(4))) float f32x4;
typedef __attribute__((ext_vector_type(4))) unsigned int u32x4;

#define TOKENS 3136
#define CC 768
#define KVC 1536
#define S196 196
#define M_ROWS 25088   // 16*8*196
#define BATCH 16

__device__ __forceinline__ float bf2f(bf16 x) { return (float)x; }
__device__ __forceinline__ bf16 f2bf(float x) { return (bf16)x; }

__device__ __forceinline__ float gelu_exact(float x) {
    return 0.5f * x * (1.0f + erff(x * 0.70710678118654752f));
}

__device__ __forceinline__ unsigned int packbf(float a, float b) {
    bf16x2 v; v[0] = (bf16)a; v[1] = (bf16)b;
    return __builtin_bit_cast(unsigned int, v);
}

// ---------------------------------------------------------------------------
// Weight transpose + bf16 convert: Wt[n][k] = W[k][n]   (fp32 input)
// ---------------------------------------------------------------------------
__global__ __launch_bounds__(256)
void transpose_w(const float* __restrict__ W, bf16* __restrict__ Wt, int K, int N)
{
    __shared__ float tle[32][33];
    int k0 = blockIdx.x * 32, n0 = blockIdx.y * 32;
    int tx = threadIdx.x & 31, ty = threadIdx.x >> 5;   // 8 rows of 32
    for (int r = ty; r < 32; r += 8)
        tle[r][tx] = W[(long)(k0 + r) * N + n0 + tx];
    __syncthreads();
    for (int r = ty; r < 32; r += 8)
        Wt[(long)(n0 + r) * K + k0 + tx] = f2bf(tle[tx][r]);
}

// ---------------------------------------------------------------------------
// Bias convert (fp32 -> bf16) into packed ws array
// ---------------------------------------------------------------------------
__global__ __launch_bounds__(256)
void conv_bias(const float* b0, const float* b1, const float* b2,
               const float* b3, const float* b4, const float* b5,
               bf16* __restrict__ dst)
{
    const float* srcs[6] = {b0, b1, b2, b3, b4, b5};
    const int sizes[6]   = {768, 1536, 768, 1536, 768, 768};
    const int offs[6]    = {0, 768, 2304, 3072, 4608, 5376};
    int which = blockIdx.x;
    const float* s = srcs[which];
    int n = sizes[which];
    bf16* d = dst + offs[which];
    for (int i = threadIdx.x; i < n; i += 256)
        d[i] = f2bf(s[i]);
}

// ---------------------------------------------------------------------------
// Reorder x_in (b, nt, nh, nw, t, c) fp32 -> bf16 x_a / x_d rows
// ---------------------------------------------------------------------------
__global__ __launch_bounds__(256)
void reorder_split(const float* __restrict__ x_in, bf16* __restrict__ xa,
                   bf16* __restrict__ xd)
{
    long idx = (long)blockIdx.x * 256 + threadIdx.x;
    const long total = (long)BATCH * 16 * S196 * 96;
    if (idx >= total) return;
    int  c8  = (int)(idx % 96) * 8;
    long row = idx / 96;
    int  s   = (int)(row % S196);
    long r2  = row / S196;
    int  tt  = (int)(r2 & 15);
    int  b   = (int)(r2 >> 4);
    int  nt  = tt >> 2, t = tt & 3;
    int  nh  = s / 14,  nw = s % 14;
    long src  = ((long)b * TOKENS + ((nt * 14 + nh) * 14 + nw) * 4 + t) * CC + c8;
    bf16* dst = (tt & 1) ? xd : xa;
    long doff = ((long)(b * 8 + (tt >> 1)) * S196 + s) * CC + c8;
    const float* sp = x_in + src;
    f32x4 a = *(const f32x4*)sp;
    f32x4 c = *(const f32x4*)(sp + 4);
    bf16x8 v;
    v[0] = f2bf(a[0]); v[1] = f2bf(a[1]); v[2] = f2bf(a[2]); v[3] = f2bf(a[3]);
    v[4] = f2bf(c[0]); v[5] = f2bf(c[1]); v[6] = f2bf(c[2]); v[7] = f2bf(c[3]);
    *(bf16x8*)(dst + doff) = v;
}

// ---------------------------------------------------------------------------
// GEMM: C = A(MxK) @ Bt(NxK)^T + bias, bf16 in/out, fp32 accum via MFMA.
// EPI: 0 -> C = x ; 1 -> C = res - gelu(x) ; 2 -> C = res + gelu(x)
// ---------------------------------------------------------------------------
template<int EPI>
__global__ __launch_bounds__(256)
void gemm_bt(const bf16* __restrict__ A, const bf16* __restrict__ Bt,
             const bf16* __restrict__ bias, const bf16* __restrict__ res,
             bf16* __restrict__ C, int N, int K)
{
    constexpr int BM = 128, BN = 128, BK = 32, LSTR = 40;
    __shared__ bf16 sA[BM * LSTR];
    __shared__ bf16 sB[BN * LSTR];
    const int tid  = threadIdx.x;
    const int lane = tid & 63, wave = tid >> 6;
    const int wm   = wave >> 1, wn = wave & 1;
    const int quad = lane >> 4, l16 = lane & 15;
    const long m0 = (long)blockIdx.x * BM;
    const long n0 = (long)blockIdx.y * BN;

    f32x4 acc[4][4] = {};

    for (int kt = 0; kt < K; kt += BK) {
        if (kt) __syncthreads();
        #pragma unroll
        for (int c = 0; c < 2; ++c) {
            int ci = tid + c * 256;
            int r  = ci >> 2, kc = ci & 3;
            bf16x8 av = *(const bf16x8*)(A  + (m0 + r) * K + kt + kc * 8);
            bf16x8 bv = *(const bf16x8*)(Bt + (n0 + r) * K + kt + kc * 8);
            *(bf16x8*)(sA + r * LSTR + kc * 8) = av;
            *(bf16x8*)(sB + r * LSTR + kc * 8) = bv;
        }
        __syncthreads();

        bf16x8 af[4], bfr[4];
        #pragma unroll
        for (int mi = 0; mi < 4; ++mi)
            af[mi] = *(const bf16x8*)(sA + (wm * 64 + mi * 16 + l16) * LSTR + quad * 8);
        #pragma unroll
        for (int ni = 0; ni < 4; ++ni)
            bfr[ni] = *(const bf16x8*)(sB + (wn * 64 + ni * 16 + l16) * LSTR + quad * 8);
        #pragma unroll
        for (int mi = 0; mi < 4; ++mi)
            #pragma unroll
            for (int ni = 0; ni < 4; ++ni)
                acc[mi][ni] = __builtin_amdgcn_mfma_f32_16x16x32_bf16(af[mi], bfr[ni], acc[mi][ni], 0, 0, 0);
    }

    #pragma unroll
    for (int mi = 0; mi < 4; ++mi) {
        #pragma unroll
        for (int ni = 0; ni < 4; ++ni) {
            int mg = (int)m0 + wm * 64 + mi * 16 + quad * 4;
            int ng = (int)n0 + wn * 64 + ni * 16 + l16;
            float bn = bf2f(bias[ng]);
            #pragma unroll
            for (int r = 0; r < 4; ++r) {
                float x = acc[mi][ni][r] + bn;
                long off = (long)(mg + r) * N + ng;
                if (EPI == 0)      C[off] = f2bf(x);
                else if (EPI == 1) C[off] = f2bf(bf2f(res[off]) - gelu_exact(x));
                else               C[off] = f2bf(bf2f(res[off]) + gelu_exact(x));
            }
        }
    }
}

// ---------------------------------------------------------------------------
// MFMA attention. One block per (head h, instance bj). 4 waves.
// Computes St = K·Q^T (16x16x32 MFMA), softmax over k (in-register),
// then O^T = V^T·P^T with P^T B-fragments built via ds_bpermute (no LDS
// round-trip). K in LDS row-major (stride 72, 2-way=free), V^T in LDS
// (stride 232, 2-way). Q fragments straight from global.
// ---------------------------------------------------------------------------
#define KSTR 72
#define VSTR 232

__global__ __launch_bounds__(256)
void attn_mfma(const bf16* __restrict__ Q, const bf16* __restrict__ KV,
               bf16* __restrict__ O)
{
    const int h  = blockIdx.x;   // 12
    const int bj = blockIdx.y;   // 128
    __shared__ bf16 Ks[208 * KSTR];   // 29,952 B  (k-token rows, d cols)
    __shared__ bf16 Vt[64 * VSTR];    // 29,696 B  (d rows, token cols, 224 used)
    const int tid = threadIdx.x, lane = tid & 63, wave = tid >> 6;
    const int quad = lane >> 4, l16 = lane & 15;

    const bf16* qg = Q  + (long)bj * S196 * CC  + h * 64;
    const bf16* kg = KV + (long)bj * S196 * KVC + h * 64;
    const bf16* vg = kg + CC;

    // stage K rows 0..207 (>=196 zeroed), 16B chunks, coalesced
    for (int i = tid; i < 208 * 8; i += 256) {
        int r = i >> 3, c8 = (i & 7) * 8;
        bf16x8 v = {};
        if (r < S196) v = *(const bf16x8*)(kg + (long)r * KVC + c8);
        *(bf16x8*)(Ks + r * KSTR + c8) = v;
    }
    // stage V transposed: Vt[d][tok], tok 0..223 (>=196 zeroed)
    for (int i = tid; i < 224 * 64; i += 256) {
        int d = i & 63, tok = i >> 6;
        bf16 v = f2bf(0.f);
        if (tok < S196) v = vg[(long)tok * KVC + d];
        Vt[d * VSTR + tok] = v;
    }
    __syncthreads();

    for (int qt = wave; qt < 13; qt += 4) {
        // B-fragments of Q^T from global: B[k=d][n=q] = Q[q][d]
        int qrow = qt * 16 + l16; if (qrow > 195) qrow = 195;
        const bf16* qrp = qg + (long)qrow * CC + quad * 8;
        bf16x8 qf0 = *(const bf16x8*)(qrp);
        bf16x8 qf1 = *(const bf16x8*)(qrp + 32);

        // St = K·Q^T : lane holds q=l16, k = rt*16 + quad*4 + r
        f32x4 st[13];
        #pragma unroll
        for (int rt = 0; rt < 13; ++rt) st[rt] = (f32x4){0.f, 0.f, 0.f, 0.f};
        #pragma unroll
        for (int rt = 0; rt < 13; ++rt) {
            const bf16* kb = Ks + (rt * 16 + l16) * KSTR + quad * 8;
            bf16x8 kf0 = *(const bf16x8*)(kb);
            bf16x8 kf1 = *(const bf16x8*)(kb + 32);
            st[rt] = __builtin_amdgcn_mfma_f32_16x16x32_bf16(kf0, qf0, st[rt], 0, 0, 0);
            st[rt] = __builtin_amdgcn_mfma_f32_16x16x32_bf16(kf1, qf1, st[rt], 0, 0, 0);
        }

        // scale + mask (k >= 196 lives in tile 12, quads 1..3)
        const float SC = 0.125f;
        #pragma unroll
        for (int rt = 0; rt < 13; ++rt) {
            st[rt][0] *= SC; st[rt][1] *= SC; st[rt][2] *= SC; st[rt][3] *= SC;
        }
        if (quad != 0)
            st[12] = (f32x4){-1e30f, -1e30f, -1e30f, -1e30f};

        // softmax over k: in-lane over 13x4, then across quads (xor 16, 32)
        float m = -1e30f;
        #pragma unroll
        for (int rt = 0; rt < 13; ++rt)
            m = fmaxf(m, fmaxf(fmaxf(st[rt][0], st[rt][1]), fmaxf(st[rt][2], st[rt][3])));
        m = fmaxf(m, __shfl_xor(m, 16, 64));
        m = fmaxf(m, __shfl_xor(m, 32, 64));
        float sum = 0.f;
        #pragma unroll
        for (int rt = 0; rt < 13; ++rt) {
            st[rt][0] = __expf(st[rt][0] - m);
            st[rt][1] = __expf(st[rt][1] - m);
            st[rt][2] = __expf(st[rt][2] - m);
            st[rt][3] = __expf(st[rt][3] - m);
            sum += st[rt][0] + st[rt][1] + st[rt][2] + st[rt][3];
        }
        sum += __shfl_xor(sum, 16, 64);
        sum += __shfl_xor(sum, 32, 64);
        float inv = 1.0f / sum;

        // p -> bf16, packed pairs: pk[rt][0]=(r0,r1), [1]=(r2,r3)
        unsigned int pk[13][2];
        #pragma unroll
        for (int rt = 0; rt < 13; ++rt) {
            pk[rt][0] = packbf(st[rt][0] * inv, st[rt][1] * inv);
            pk[rt][1] = packbf(st[rt][2] * inv, st[rt][3] * inv);
        }

        // O^T = V^T·P^T. 7 k-chunks of 32 (tiles 2c, 2c+1; tile 13 = 0).
        // B-frag element pair (j=2jp,2jp+1): k = 8*quad + 2jp+{0,1};
        // source lane = ((quad&1)*2 + (jp>>1))*16 + l16, reg pair = jp&1,
        // tile select = quad>>1.
        f32x4 ot[4];
        #pragma unroll
        for (int dt = 0; dt < 4; ++dt) ot[dt] = (f32x4){0.f, 0.f, 0.f, 0.f};
        #pragma unroll
        for (int c = 0; c < 7; ++c) {
            u32x4 fp;
            #pragma unroll
            for (int jp = 0; jp < 4; ++jp) {
                int jh = jp >> 1, rp = jp & 1;
                int srcb = ((((quad & 1) << 1) + jh) << 6) | (l16 << 2);
                int a = __builtin_amdgcn_ds_bpermute(srcb, (int)pk[2 * c][rp]);
                int b = (c < 6) ? __builtin_amdgcn_ds_bpermute(srcb, (int)pk[2 * c + 1][rp]) : 0;
                fp[jp] = (quad >> 1) ? (unsigned int)b : (unsigned int)a;
            }
            bf16x8 pB = __builtin_bit_cast(bf16x8, fp);
            #pragma unroll
            for (int dt = 0; dt < 4; ++dt) {
                bf16x8 vf = *(const bf16x8*)(Vt + (dt * 16 + l16) * VSTR + c * 32 + quad * 8);
                ot[dt] = __builtin_amdgcn_mfma_f32_16x16x32_bf16(vf, pB, ot[dt], 0, 0, 0);
            }
        }

        // store O: C-layout of O^T: col=l16=q, row=quad*4+r=d (within dt*16)
        int token = qt * 16 + l16;
        if (token < S196) {
            bf16* op = O + ((long)bj * S196 + token) * CC + h * 64 + quad * 4;
            #pragma unroll
            for (int dt = 0; dt < 4; ++dt) {
                bf16x4 v;
                v[0] = f2bf(ot[dt][0]); v[1] = f2bf(ot[dt][1]);
                v[2] = f2bf(ot[dt][2]); v[3] = f2bf(ot[dt][3]);
                *(bf16x4*)(op + dt * 16) = v;
            }
        }
    }
}

// ---------------------------------------------------------------------------
// Outputs (fp32): pool_a = mean_c((x_e+x_o)/2) - mean_c(x_a_new)
//                 x_d_out = mean_c(x_d_new)
// ---------------------------------------------------------------------------
__global__ __launch_bounds__(256)
void out_reduce(const float* __restrict__ x_in, const bf16* __restrict__ xa,
                const bf16* __restrict__ xd, float* __restrict__ out)
{
    int id = blockIdx.x;
    int s  = id % S196;
    int bj = id / S196;
    int j  = bj & 7, b = bj >> 3;
    int tid = threadIdx.x, lane = tid & 63, wave = tid >> 6;
    int nh = s / 14, nw = s % 14;

    float sum = 0.f;
    if (wave < 2) {
        int tt = 2 * j + wave;
        int nt = tt >> 2, t = tt & 3;
        const float* p = x_in + ((long)b * TOKENS + ((nt * 14 + nh) * 14 + nw) * 4 + t) * CC;
        for (int c = lane; c < CC; c += 64) sum += p[c];
    } else {
        const bf16* p = (wave == 2 ? xa : xd) + (long)id * CC;
        for (int c = lane; c < CC; c += 64) sum += bf2f(p[c]);
    }
    #pragma unroll
    for (int off = 32; off; off >>= 1) sum += __shfl_xor(sum, off, 64);

    __shared__ float r4[4];
    if (lane == 0) r4[wave] = sum;
    __syncthreads();
    if (tid == 0) {
        const float invC = 1.0f / 768.0f;
        out[id]          = (r4[0] + r4[1]) * 0.5f * invC - r4[2] * invC;
        out[M_ROWS + id] = r4[3] * invC;
    }
}

// ---------------------------------------------------------------------------
extern "C" void kernel_launch(void* const* d_in, const int* in_sizes, int n_in,
                              void* d_out, int out_size, void* d_ws, size_t ws_size,
                              hipStream_t stream)
{
    const float* x_in  = (const float*)d_in[0];
    const float* Wq_d  = (const float*)d_in[1];
    const float* bq_d  = (const float*)d_in[2];
    const float* Wkv_a = (const float*)d_in[3];
    const float* bkv_a = (const float*)d_in[4];
    const float* Wq_a  = (const float*)d_in[5];
    const float* bq_a  = (const float*)d_in[6];
    const float* Wkv_d = (const float*)d_in[7];
    const float* bkv_d = (const float*)d_in[8];
    const float* Wp_d  = (const float*)d_in[9];
    const float* bp_d  = (const float*)d_in[10];
    const float* Wp_a  = (const float*)d_in[11];
    const float* bp_a  = (const float*)d_in[12];
    float* out = (float*)d_out;

    char* w = (char*)d_ws;
    auto alloc = [&](size_t elems) {
        bf16* p = (bf16*)w;
        w += ((elems * 2 + 255) / 256) * 256;
        return p;
    };
    bf16* biasAll = alloc(6144);
    bf16* WtQd = alloc((size_t)768 * 768);
    bf16* WtKa = alloc((size_t)1536 * 768);
    bf16* WtQa = alloc((size_t)768 * 768);
    bf16* WtKd = alloc((size_t)1536 * 768);
    bf16* WtPd = alloc((size_t)768 * 768);
    bf16* WtPa = alloc((size_t)768 * 768);
    bf16* xa   = alloc((size_t)M_ROWS * 768);
    bf16* xd   = alloc((size_t)M_ROWS * 768);
    bf16* Qb   = alloc((size_t)M_ROWS * 768);
    bf16* KVb  = alloc((size_t)M_ROWS * 1536);
    bf16* Ob   = alloc((size_t)M_ROWS * 768);

    dim3 blk(256);
    transpose_w<<<dim3(24, 24), blk, 0, stream>>>(Wq_d,  WtQd, 768, 768);
    transpose_w<<<dim3(24, 48), blk, 0, stream>>>(Wkv_a, WtKa, 768, 1536);
    transpose_w<<<dim3(24, 24), blk, 0, stream>>>(Wq_a,  WtQa, 768, 768);
    transpose_w<<<dim3(24, 48), blk, 0, stream>>>(Wkv_d, WtKd, 768, 1536);
    transpose_w<<<dim3(24, 24), blk, 0, stream>>>(Wp_d,  WtPd, 768, 768);
    transpose_w<<<dim3(24, 24), blk, 0, stream>>>(Wp_a,  WtPa, 768, 768);
    conv_bias<<<dim3(6), blk, 0, stream>>>(bq_d, bkv_a, bq_a, bkv_d, bp_d, bp_a, biasAll);

    long total_chunks = (long)BATCH * 16 * S196 * 96;
    int  rblocks = (int)((total_chunks + 255) / 256);
    reorder_split<<<rblocks, blk, 0, stream>>>(x_in, xa, xd);

    const bf16* Bq_d  = biasAll;
    const bf16* Bkv_a = biasAll + 768;
    const bf16* Bq_a  = biasAll + 2304;
    const bf16* Bkv_d = biasAll + 3072;
    const bf16* Bp_d  = biasAll + 4608;
    const bf16* Bp_a  = biasAll + 5376;

    dim3 g768(196, 6), g1536(196, 12);

    // Phase 1: _d = attn(q=x_d, kv=x_a); x_d -= gelu(_d @ Wp_d + bp_d)
    gemm_bt<0><<<g768,  blk, 0, stream>>>(xd, WtQd, Bq_d,  nullptr, Qb,  768,  768);
    gemm_bt<0><<<g1536, blk, 0, stream>>>(xa, WtKa, Bkv_a, nullptr, KVb, 1536, 768);
    attn_mfma<<<dim3(12, 128), blk, 0, stream>>>(Qb, KVb, Ob);
    gemm_bt<1><<<g768,  blk, 0, stream>>>(Ob, WtPd, Bp_d,  xd,      xd,  768,  768);

    // Phase 2: _a = attn(q=x_a, kv=x_d_new); x_a += gelu(_a @ Wp_a + bp_a)
    gemm_bt<0><<<g768,  blk, 0, stream>>>(xa, WtQa, Bq_a,  nullptr, Qb,  768,  768);
    gemm_bt<0><<<g1536, blk, 0, stream>>>(xd, WtKd, Bkv_d, nullptr, KVb, 1536, 768);
    attn_mfma<<<dim3(12, 128), blk, 0, stream>>>(Qb, KVb, Ob);
    gemm_bt<2><<<g768,  blk, 0, stream>>>(Ob, WtPa, Bp_a,  xa,      xa,  768,  768);

    out_reduce<<<M_ROWS, blk, 0, stream>>>(x_in, xa, xd, out);
}

// Round 5
// 984.408 us; speedup vs baseline: 3.8781x; 1.1477x over previous
//
#include <hip/hip_runtime.h>

typedef __bf16 bf16;
typedef __attribute__((ext_vector_type(8))) __bf16 bf16x8;
typedef __attribute__((ext_vector_type(4))) __bf16 bf16x4;
typedef __attribute__((ext_vector_type(2))) __bf16 bf16x2;
typedef __attribute__((ext_vector_type(4))) float f32x4;
typedef __attribute__((ext_vector_type(4))) unsigned int u32x4;

#define TOKENS 3136
#define CC 768
#define KVC 1536
#define S196 196
#define M_ROWS 25088   // 16*8*196
#define BATCH 16

__device__ __forceinline__ float bf2f(bf16 x) { return (float)x; }
__device__ __forceinline__ bf16 f2bf(float x) { return (bf16)x; }

__device__ __forceinline__ float gelu_exact(float x) {
    return 0.5f * x * (1.0f + erff(x * 0.70710678118654752f));
}

__device__ __forceinline__ unsigned int packbf(float a, float b) {
    bf16x2 v; v[0] = (bf16)a; v[1] = (bf16)b;
    return __builtin_bit_cast(unsigned int, v);
}

// async global->LDS, 16B per lane; LDS dest = wave-uniform base + lane*16
#define GLOAD_LDS16(gp, lp) \
    __builtin_amdgcn_global_load_lds((const __attribute__((address_space(1))) void*)(gp), \
                                     (__attribute__((address_space(3))) void*)(lp), 16, 0, 0)

// ---------------------------------------------------------------------------
// Weight transpose + bf16 convert: Wt[n][k] = W[k][n]   (fp32 input)
// ---------------------------------------------------------------------------
__global__ __launch_bounds__(256)
void transpose_w(const float* __restrict__ W, bf16* __restrict__ Wt, int K, int N)
{
    __shared__ float tle[32][33];
    int k0 = blockIdx.x * 32, n0 = blockIdx.y * 32;
    int tx = threadIdx.x & 31, ty = threadIdx.x >> 5;   // 8 rows of 32
    for (int r = ty; r < 32; r += 8)
        tle[r][tx] = W[(long)(k0 + r) * N + n0 + tx];
    __syncthreads();
    for (int r = ty; r < 32; r += 8)
        Wt[(long)(n0 + r) * K + k0 + tx] = f2bf(tle[tx][r]);
}

// ---------------------------------------------------------------------------
// Bias convert (fp32 -> bf16) into packed ws array
// ---------------------------------------------------------------------------
__global__ __launch_bounds__(256)
void conv_bias(const float* b0, const float* b1, const float* b2,
               const float* b3, const float* b4, const float* b5,
               bf16* __restrict__ dst)
{
    const float* srcs[6] = {b0, b1, b2, b3, b4, b5};
    const int sizes[6]   = {768, 1536, 768, 1536, 768, 768};
    const int offs[6]    = {0, 768, 2304, 3072, 4608, 5376};
    int which = blockIdx.x;
    const float* s = srcs[which];
    int n = sizes[which];
    bf16* d = dst + offs[which];
    for (int i = threadIdx.x; i < n; i += 256)
        d[i] = f2bf(s[i]);
}

// ---------------------------------------------------------------------------
// Reorder x_in (b, nt, nh, nw, t, c) fp32 -> bf16 x_a / x_d rows
// ---------------------------------------------------------------------------
__global__ __launch_bounds__(256)
void reorder_split(const float* __restrict__ x_in, bf16* __restrict__ xa,
                   bf16* __restrict__ xd)
{
    long idx = (long)blockIdx.x * 256 + threadIdx.x;
    const long total = (long)BATCH * 16 * S196 * 96;
    if (idx >= total) return;
    int  c8  = (int)(idx % 96) * 8;
    long row = idx / 96;
    int  s   = (int)(row % S196);
    long r2  = row / S196;
    int  tt  = (int)(r2 & 15);
    int  b   = (int)(r2 >> 4);
    int  nt  = tt >> 2, t = tt & 3;
    int  nh  = s / 14,  nw = s % 14;
    long src  = ((long)b * TOKENS + ((nt * 14 + nh) * 14 + nw) * 4 + t) * CC + c8;
    bf16* dst = (tt & 1) ? xd : xa;
    long doff = ((long)(b * 8 + (tt >> 1)) * S196 + s) * CC + c8;
    const float* sp = x_in + src;
    f32x4 a = *(const f32x4*)sp;
    f32x4 c = *(const f32x4*)(sp + 4);
    bf16x8 v;
    v[0] = f2bf(a[0]); v[1] = f2bf(a[1]); v[2] = f2bf(a[2]); v[3] = f2bf(a[3]);
    v[4] = f2bf(c[0]); v[5] = f2bf(c[1]); v[6] = f2bf(c[2]); v[7] = f2bf(c[3]);
    *(bf16x8*)(dst + doff) = v;
}

// ---------------------------------------------------------------------------
// GEMM (m97 structure): C = A(MxK) @ Bt(NxK)^T + bias, bf16 in/out.
// 128x128x32 tile, global_load_lds width=16 staging, no LDS pad.
// EPI: 0 -> C = x ; 1 -> C = res - gelu(x) ; 2 -> C = res + gelu(x)
// ---------------------------------------------------------------------------
template<int EPI>
__global__ __launch_bounds__(256)
void gemm_bt(const bf16* __restrict__ A, const bf16* __restrict__ Bt,
             const bf16* __restrict__ bias, const bf16* __restrict__ res,
             bf16* __restrict__ C, int N, int K)
{
    constexpr int BM = 128, BN = 128, BK = 32;
    __shared__ alignas(16) bf16 sA[BM * BK];
    __shared__ alignas(16) bf16 sB[BN * BK];
    const int tid  = threadIdx.x;
    const int lane = tid & 63, wave = tid >> 6;
    const int wm   = wave >> 1, wn = wave & 1;
    const int quad = lane >> 4, l16 = lane & 15;
    const long m0 = (long)blockIdx.x * BM;
    const long n0 = (long)blockIdx.y * BN;

    f32x4 acc[4][4] = {};

    for (int kt = 0; kt < K; kt += BK) {
        if (kt) __syncthreads();
        // 512 chunks of 16B per tile; wave w, pass c covers chunks (w*2+c)*64 + lane.
        // LDS dest: wave-uniform base + lane*16 -> row-major r*BK + kc*8 (no pad).
        #pragma unroll
        for (int c = 0; c < 2; ++c) {
            int ci = (wave * 2 + c) * 64 + lane;
            int r  = ci >> 2, kc = ci & 3;
            const bf16* ga = A  + (m0 + r) * K + kt + kc * 8;
            const bf16* gb = Bt + (n0 + r) * K + kt + kc * 8;
            bf16* la = sA + (wave * 2 + c) * 512;
            bf16* lb = sB + (wave * 2 + c) * 512;
            GLOAD_LDS16(ga, la);
            GLOAD_LDS16(gb, lb);
        }
        __syncthreads();

        bf16x8 af[4], bfr[4];
        #pragma unroll
        for (int mi = 0; mi < 4; ++mi)
            af[mi] = *(const bf16x8*)(sA + (wm * 64 + mi * 16 + l16) * BK + quad * 8);
        #pragma unroll
        for (int ni = 0; ni < 4; ++ni)
            bfr[ni] = *(const bf16x8*)(sB + (wn * 64 + ni * 16 + l16) * BK + quad * 8);
        #pragma unroll
        for (int mi = 0; mi < 4; ++mi)
            #pragma unroll
            for (int ni = 0; ni < 4; ++ni)
                acc[mi][ni] = __builtin_amdgcn_mfma_f32_16x16x32_bf16(af[mi], bfr[ni], acc[mi][ni], 0, 0, 0);
    }

    // Epilogue. D layout: col = lane&15, row = quad*4 + r
    #pragma unroll
    for (int mi = 0; mi < 4; ++mi) {
        #pragma unroll
        for (int ni = 0; ni < 4; ++ni) {
            int mg = (int)m0 + wm * 64 + mi * 16 + quad * 4;
            int ng = (int)n0 + wn * 64 + ni * 16 + l16;
            float bn = bf2f(bias[ng]);
            #pragma unroll
            for (int r = 0; r < 4; ++r) {
                float x = acc[mi][ni][r] + bn;
                long off = (long)(mg + r) * N + ng;
                if (EPI == 0)      C[off] = f2bf(x);
                else if (EPI == 1) C[off] = f2bf(bf2f(res[off]) - gelu_exact(x));
                else               C[off] = f2bf(bf2f(res[off]) + gelu_exact(x));
            }
        }
    }
}

// ---------------------------------------------------------------------------
// MFMA attention. One block per (head h, instance bj). 4 waves.
// St = K·Q^T (16x16x32), in-register softmax over k, O^T = V^T·P^T with
// P^T B-fragments built via ds_bpermute. V^T staged with token-=-lane
// mapping (2-way LDS writes = free). VSTR=264: mult-of-8 (b128 align),
// 264/2 = 4 mod 32 spreads PV-read rows across banks.
// ---------------------------------------------------------------------------
#define KSTR 72
#define VSTR 264

__global__ __launch_bounds__(256)
void attn_mfma(const bf16* __restrict__ Q, const bf16* __restrict__ KV,
               bf16* __restrict__ O)
{
    const int h  = blockIdx.x;   // 12
    const int bj = blockIdx.y;   // 128
    __shared__ alignas(16) bf16 Ks[208 * KSTR];   // 29,952 B
    __shared__ alignas(16) bf16 Vt[64 * VSTR];    // 33,792 B  (tok 0..255, >=196 zero)
    const int tid = threadIdx.x, lane = tid & 63, wave = tid >> 6;
    const int quad = lane >> 4, l16 = lane & 15;

    const bf16* qg = Q  + (long)bj * S196 * CC  + h * 64;
    const bf16* kg = KV + (long)bj * S196 * KVC + h * 64;
    const bf16* vg = kg + CC;

    // stage K rows 0..207 (>=196 zeroed), 16B chunks, coalesced
    for (int i = tid; i < 208 * 8; i += 256) {
        int r = i >> 3, c8 = (i & 7) * 8;
        bf16x8 v = {};
        if (r < S196) v = *(const bf16x8*)(kg + (long)r * KVC + c8);
        *(bf16x8*)(Ks + r * KSTR + c8) = v;
    }
    // stage V transposed: lane-consecutive tokens -> 2-way (free) LDS writes
    for (int i = tid; i < 256 * 8; i += 256) {
        int g   = i >> 6;                    // wave-uniform group 0..31
        int c8  = (g & 7) * 8;
        int tok = (g >> 3) * 64 + (i & 63);  // 0..255
        bf16x8 v = {};
        if (tok < S196) v = *(const bf16x8*)(vg + (long)tok * KVC + c8);
        #pragma unroll
        for (int j = 0; j < 8; ++j)
            Vt[(c8 + j) * VSTR + tok] = v[j];
    }
    __syncthreads();

    for (int qt = wave; qt < 13; qt += 4) {
        // B-fragments of Q^T from global: B[k=d][n=q] = Q[q][d]
        int qrow = qt * 16 + l16; if (qrow > 195) qrow = 195;
        const bf16* qrp = qg + (long)qrow * CC + quad * 8;
        bf16x8 qf0 = *(const bf16x8*)(qrp);
        bf16x8 qf1 = *(const bf16x8*)(qrp + 32);

        // St = K·Q^T : lane holds q=l16, k = rt*16 + quad*4 + r
        f32x4 st[13];
        #pragma unroll
        for (int rt = 0; rt < 13; ++rt) st[rt] = (f32x4){0.f, 0.f, 0.f, 0.f};
        #pragma unroll
        for (int rt = 0; rt < 13; ++rt) {
            const bf16* kb = Ks + (rt * 16 + l16) * KSTR + quad * 8;
            bf16x8 kf0 = *(const bf16x8*)(kb);
            bf16x8 kf1 = *(const bf16x8*)(kb + 32);
            st[rt] = __builtin_amdgcn_mfma_f32_16x16x32_bf16(kf0, qf0, st[rt], 0, 0, 0);
            st[rt] = __builtin_amdgcn_mfma_f32_16x16x32_bf16(kf1, qf1, st[rt], 0, 0, 0);
        }

        const float SC = 0.125f;
        #pragma unroll
        for (int rt = 0; rt < 13; ++rt) {
            st[rt][0] *= SC; st[rt][1] *= SC; st[rt][2] *= SC; st[rt][3] *= SC;
        }
        if (quad != 0)
            st[12] = (f32x4){-1e30f, -1e30f, -1e30f, -1e30f};

        float m = -1e30f;
        #pragma unroll
        for (int rt = 0; rt < 13; ++rt)
            m = fmaxf(m, fmaxf(fmaxf(st[rt][0], st[rt][1]), fmaxf(st[rt][2], st[rt][3])));
        m = fmaxf(m, __shfl_xor(m, 16, 64));
        m = fmaxf(m, __shfl_xor(m, 32, 64));
        float sum = 0.f;
        #pragma unroll
        for (int rt = 0; rt < 13; ++rt) {
            st[rt][0] = __expf(st[rt][0] - m);
            st[rt][1] = __expf(st[rt][1] - m);
            st[rt][2] = __expf(st[rt][2] - m);
            st[rt][3] = __expf(st[rt][3] - m);
            sum += st[rt][0] + st[rt][1] + st[rt][2] + st[rt][3];
        }
        sum += __shfl_xor(sum, 16, 64);
        sum += __shfl_xor(sum, 32, 64);
        float inv = 1.0f / sum;

        unsigned int pk[13][2];
        #pragma unroll
        for (int rt = 0; rt < 13; ++rt) {
            pk[rt][0] = packbf(st[rt][0] * inv, st[rt][1] * inv);
            pk[rt][1] = packbf(st[rt][2] * inv, st[rt][3] * inv);
        }

        // O^T = V^T·P^T, P^T B-fragments via ds_bpermute
        f32x4 ot[4];
        #pragma unroll
        for (int dt = 0; dt < 4; ++dt) ot[dt] = (f32x4){0.f, 0.f, 0.f, 0.f};
        #pragma unroll
        for (int c = 0; c < 7; ++c) {
            u32x4 fp;
            #pragma unroll
            for (int jp = 0; jp < 4; ++jp) {
                int jh = jp >> 1, rp = jp & 1;
                int srcb = ((((quad & 1) << 1) + jh) << 6) | (l16 << 2);
                int a = __builtin_amdgcn_ds_bpermute(srcb, (int)pk[2 * c][rp]);
                int b = (c < 6) ? __builtin_amdgcn_ds_bpermute(srcb, (int)pk[2 * c + 1][rp]) : 0;
                fp[jp] = (quad >> 1) ? (unsigned int)b : (unsigned int)a;
            }
            bf16x8 pB = __builtin_bit_cast(bf16x8, fp);
            #pragma unroll
            for (int dt = 0; dt < 4; ++dt) {
                bf16x8 vf = *(const bf16x8*)(Vt + (dt * 16 + l16) * VSTR + c * 32 + quad * 8);
                ot[dt] = __builtin_amdgcn_mfma_f32_16x16x32_bf16(vf, pB, ot[dt], 0, 0, 0);
            }
        }

        int token = qt * 16 + l16;
        if (token < S196) {
            bf16* op = O + ((long)bj * S196 + token) * CC + h * 64 + quad * 4;
            #pragma unroll
            for (int dt = 0; dt < 4; ++dt) {
                bf16x4 v;
                v[0] = f2bf(ot[dt][0]); v[1] = f2bf(ot[dt][1]);
                v[2] = f2bf(ot[dt][2]); v[3] = f2bf(ot[dt][3]);
                *(bf16x4*)(op + dt * 16) = v;
            }
        }
    }
}

// ---------------------------------------------------------------------------
// Outputs (fp32): pool_a = mean_c((x_e+x_o)/2) - mean_c(x_a_new)
//                 x_d_out = mean_c(x_d_new)
// ---------------------------------------------------------------------------
__global__ __launch_bounds__(256)
void out_reduce(const float* __restrict__ x_in, const bf16* __restrict__ xa,
                const bf16* __restrict__ xd, float* __restrict__ out)
{
    int id = blockIdx.x;
    int s  = id % S196;
    int bj = id / S196;
    int j  = bj & 7, b = bj >> 3;
    int tid = threadIdx.x, lane = tid & 63, wave = tid >> 6;
    int nh = s / 14, nw = s % 14;

    float sum = 0.f;
    if (wave < 2) {
        int tt = 2 * j + wave;
        int nt = tt >> 2, t = tt & 3;
        const float* p = x_in + ((long)b * TOKENS + ((nt * 14 + nh) * 14 + nw) * 4 + t) * CC;
        for (int c = lane; c < CC; c += 64) sum += p[c];
    } else {
        const bf16* p = (wave == 2 ? xa : xd) + (long)id * CC;
        for (int c = lane; c < CC; c += 64) sum += bf2f(p[c]);
    }
    #pragma unroll
    for (int off = 32; off; off >>= 1) sum += __shfl_xor(sum, off, 64);

    __shared__ float r4[4];
    if (lane == 0) r4[wave] = sum;
    __syncthreads();
    if (tid == 0) {
        const float invC = 1.0f / 768.0f;
        out[id]          = (r4[0] + r4[1]) * 0.5f * invC - r4[2] * invC;
        out[M_ROWS + id] = r4[3] * invC;
    }
}

// ---------------------------------------------------------------------------
extern "C" void kernel_launch(void* const* d_in, const int* in_sizes, int n_in,
                              void* d_out, int out_size, void* d_ws, size_t ws_size,
                              hipStream_t stream)
{
    const float* x_in  = (const float*)d_in[0];
    const float* Wq_d  = (const float*)d_in[1];
    const float* bq_d  = (const float*)d_in[2];
    const float* Wkv_a = (const float*)d_in[3];
    const float* bkv_a = (const float*)d_in[4];
    const float* Wq_a  = (const float*)d_in[5];
    const float* bq_a  = (const float*)d_in[6];
    const float* Wkv_d = (const float*)d_in[7];
    const float* bkv_d = (const float*)d_in[8];
    const float* Wp_d  = (const float*)d_in[9];
    const float* bp_d  = (const float*)d_in[10];
    const float* Wp_a  = (const float*)d_in[11];
    const float* bp_a  = (const float*)d_in[12];
    float* out = (float*)d_out;

    char* w = (char*)d_ws;
    auto alloc = [&](size_t elems) {
        bf16* p = (bf16*)w;
        w += ((elems * 2 + 255) / 256) * 256;
        return p;
    };
    bf16* biasAll = alloc(6144);
    bf16* WtQd = alloc((size_t)768 * 768);
    bf16* WtKa = alloc((size_t)1536 * 768);
    bf16* WtQa = alloc((size_t)768 * 768);
    bf16* WtKd = alloc((size_t)1536 * 768);
    bf16* WtPd = alloc((size_t)768 * 768);
    bf16* WtPa = alloc((size_t)768 * 768);
    bf16* xa   = alloc((size_t)M_ROWS * 768);
    bf16* xd   = alloc((size_t)M_ROWS * 768);
    bf16* Qb   = alloc((size_t)M_ROWS * 768);
    bf16* KVb  = alloc((size_t)M_ROWS * 1536);
    bf16* Ob   = alloc((size_t)M_ROWS * 768);

    dim3 blk(256);
    transpose_w<<<dim3(24, 24), blk, 0, stream>>>(Wq_d,  WtQd, 768, 768);
    transpose_w<<<dim3(24, 48), blk, 0, stream>>>(Wkv_a, WtKa, 768, 1536);
    transpose_w<<<dim3(24, 24), blk, 0, stream>>>(Wq_a,  WtQa, 768, 768);
    transpose_w<<<dim3(24, 48), blk, 0, stream>>>(Wkv_d, WtKd, 768, 1536);
    transpose_w<<<dim3(24, 24), blk, 0, stream>>>(Wp_d,  WtPd, 768, 768);
    transpose_w<<<dim3(24, 24), blk, 0, stream>>>(Wp_a,  WtPa, 768, 768);
    conv_bias<<<dim3(6), blk, 0, stream>>>(bq_d, bkv_a, bq_a, bkv_d, bp_d, bp_a, biasAll);

    long total_chunks = (long)BATCH * 16 * S196 * 96;
    int  rblocks = (int)((total_chunks + 255) / 256);
    reorder_split<<<rblocks, blk, 0, stream>>>(x_in, xa, xd);

    const bf16* Bq_d  = biasAll;
    const bf16* Bkv_a = biasAll + 768;
    const bf16* Bq_a  = biasAll + 2304;
    const bf16* Bkv_d = biasAll + 3072;
    const bf16* Bp_d  = biasAll + 4608;
    const bf16* Bp_a  = biasAll + 5376;

    dim3 g768(196, 6), g1536(196, 12);

    // Phase 1: _d = attn(q=x_d, kv=x_a); x_d -= gelu(_d @ Wp_d + bp_d)
    gemm_bt<0><<<g768,  blk, 0, stream>>>(xd, WtQd, Bq_d,  nullptr, Qb,  768,  768);
    gemm_bt<0><<<g1536, blk, 0, stream>>>(xa, WtKa, Bkv_a, nullptr, KVb, 1536, 768);
    attn_mfma<<<dim3(12, 128), blk, 0, stream>>>(Qb, KVb, Ob);
    gemm_bt<1><<<g768,  blk, 0, stream>>>(Ob, WtPd, Bp_d,  xd,      xd,  768,  768);

    // Phase 2: _a = attn(q=x_a, kv=x_d_new); x_a += gelu(_a @ Wp_a + bp_a)
    gemm_bt<0><<<g768,  blk, 0, stream>>>(xa, WtQa, Bq_a,  nullptr, Qb,  768,  768);
    gemm_bt<0><<<g1536, blk, 0, stream>>>(xd, WtKd, Bkv_d, nullptr, KVb, 1536, 768);
    attn_mfma<<<dim3(12, 128), blk, 0, stream>>>(Qb, KVb, Ob);
    gemm_bt<2><<<g768,  blk, 0, stream>>>(Ob, WtPa, Bp_a,  xa,      xa,  768,  768);

    out_reduce<<<M_ROWS, blk, 0, stream>>>(x_in, xa, xd, out);
}

// Round 6
// 869.077 us; speedup vs baseline: 4.3927x; 1.1327x over previous
//
#include <hip/hip_runtime.h>

typedef __bf16 bf16;
typedef __attribute__((ext_vector_type(8))) __bf16 bf16x8;
typedef __attribute__((ext_vector_type(4))) __bf16 bf16x4;
typedef __attribute__((ext_vector_type(2))) __bf16 bf16x2;
typedef __attribute__((ext_vector_type(4))) float f32x4;
typedef __attribute__((ext_vector_type(4))) unsigned int u32x4;

#define TOKENS 3136
#define CC 768
#define S196 196
#define M_ROWS 25088   // 16*8*196
#define BATCH 16

__device__ __forceinline__ float bf2f(bf16 x) { return (float)x; }
__device__ __forceinline__ bf16 f2bf(float x) { return (bf16)x; }

__device__ __forceinline__ float gelu_exact(float x) {
    return 0.5f * x * (1.0f + erff(x * 0.70710678118654752f));
}

__device__ __forceinline__ unsigned int packbf(float a, float b) {
    bf16x2 v; v[0] = (bf16)a; v[1] = (bf16)b;
    return __builtin_bit_cast(unsigned int, v);
}

// async global->LDS, 16B per lane; LDS dest = wave-uniform base + lane*16
#define GLOAD_LDS16(gp, lp) \
    __builtin_amdgcn_global_load_lds((const __attribute__((address_space(1))) void*)(gp), \
                                     (__attribute__((address_space(3))) void*)(lp), 16, 0, 0)

// ---------------------------------------------------------------------------
// Weight transpose + bf16 convert: Wt[n][k] = W[k][n]   (fp32 input)
// ---------------------------------------------------------------------------
__global__ __launch_bounds__(256)
void transpose_w(const float* __restrict__ W, bf16* __restrict__ Wt, int K, int N)
{
    __shared__ float tle[32][33];
    int k0 = blockIdx.x * 32, n0 = blockIdx.y * 32;
    int tx = threadIdx.x & 31, ty = threadIdx.x >> 5;   // 8 rows of 32
    for (int r = ty; r < 32; r += 8)
        tle[r][tx] = W[(long)(k0 + r) * N + n0 + tx];
    __syncthreads();
    for (int r = ty; r < 32; r += 8)
        Wt[(long)(n0 + r) * K + k0 + tx] = f2bf(tle[tx][r]);
}

// ---------------------------------------------------------------------------
// Bias convert (fp32 -> bf16) into packed ws array.
// Layout: [bq_d(768) | bkv_a(1536) | bq_a(768) | bkv_d(1536) | bp_d | bp_a]
// Note bkv_a and bq_a are ADJACENT -> usable as one 2304-wide bias.
// ---------------------------------------------------------------------------
__global__ __launch_bounds__(256)
void conv_bias(const float* b0, const float* b1, const float* b2,
               const float* b3, const float* b4, const float* b5,
               bf16* __restrict__ dst)
{
    const float* srcs[6] = {b0, b1, b2, b3, b4, b5};
    const int sizes[6]   = {768, 1536, 768, 1536, 768, 768};
    const int offs[6]    = {0, 768, 2304, 3072, 4608, 5376};
    int which = blockIdx.x;
    const float* s = srcs[which];
    int n = sizes[which];
    bf16* d = dst + offs[which];
    for (int i = threadIdx.x; i < n; i += 256)
        d[i] = f2bf(s[i]);
}

// ---------------------------------------------------------------------------
// Reorder x_in (b, nt, nh, nw, t, c) fp32 -> bf16 x_a / x_d rows
// ---------------------------------------------------------------------------
__global__ __launch_bounds__(256)
void reorder_split(const float* __restrict__ x_in, bf16* __restrict__ xa,
                   bf16* __restrict__ xd)
{
    long idx = (long)blockIdx.x * 256 + threadIdx.x;
    const long total = (long)BATCH * 16 * S196 * 96;
    if (idx >= total) return;
    int  c8  = (int)(idx % 96) * 8;
    long row = idx / 96;
    int  s   = (int)(row % S196);
    long r2  = row / S196;
    int  tt  = (int)(r2 & 15);
    int  b   = (int)(r2 >> 4);
    int  nt  = tt >> 2, t = tt & 3;
    int  nh  = s / 14,  nw = s % 14;
    long src  = ((long)b * TOKENS + ((nt * 14 + nh) * 14 + nw) * 4 + t) * CC + c8;
    bf16* dst = (tt & 1) ? xd : xa;
    long doff = ((long)(b * 8 + (tt >> 1)) * S196 + s) * CC + c8;
    const float* sp = x_in + src;
    f32x4 a = *(const f32x4*)sp;
    f32x4 c = *(const f32x4*)(sp + 4);
    bf16x8 v;
    v[0] = f2bf(a[0]); v[1] = f2bf(a[1]); v[2] = f2bf(a[2]); v[3] = f2bf(a[3]);
    v[4] = f2bf(c[0]); v[5] = f2bf(c[1]); v[6] = f2bf(c[2]); v[7] = f2bf(c[3]);
    *(bf16x8*)(dst + doff) = v;
}

// ---------------------------------------------------------------------------
// Row-sum helper: sum of 768 bf16 channels, one wave per row.
// lane reads bf16x8 at lane*8 (+ lanes<32 a second at 512+lane*8).
// ---------------------------------------------------------------------------
__device__ __forceinline__ float row_sum768(const bf16* __restrict__ p, int lane)
{
    float s = 0.f;
    bf16x8 v = *(const bf16x8*)(p + lane * 8);
    #pragma unroll
    for (int j = 0; j < 8; ++j) s += bf2f(v[j]);
    if (lane < 32) {
        bf16x8 w = *(const bf16x8*)(p + 512 + lane * 8);
        #pragma unroll
        for (int j = 0; j < 8; ++j) s += bf2f(w[j]);
    }
    #pragma unroll
    for (int off = 32; off; off >>= 1) s += __shfl_xor(s, off, 64);
    return s;
}

// pool0[id] = mean_c((xa[id]+xd[id])/2)   (original xa/xd, before updates)
__global__ __launch_bounds__(256)
void pool_ad(const bf16* __restrict__ xa, const bf16* __restrict__ xd,
             float* __restrict__ pool0)
{
    int id = blockIdx.x * 4 + (threadIdx.x >> 6);
    int lane = threadIdx.x & 63;
    float sa = row_sum768(xa + (long)id * CC, lane);
    float sd = row_sum768(xd + (long)id * CC, lane);
    if (lane == 0) pool0[id] = (sa + sd) * (0.5f / 768.0f);
}

// out[id] = pool0[id] - mean_c(xa_new[id]) ; out[M+id] = mean_c(xd_new[id])
__global__ __launch_bounds__(256)
void out_final(const bf16* __restrict__ xa, const bf16* __restrict__ xd,
               const float* __restrict__ pool0, float* __restrict__ out)
{
    int id = blockIdx.x * 4 + (threadIdx.x >> 6);
    int lane = threadIdx.x & 63;
    float sa = row_sum768(xa + (long)id * CC, lane);
    float sd = row_sum768(xd + (long)id * CC, lane);
    if (lane == 0) {
        out[id]          = pool0[id] - sa * (1.0f / 768.0f);
        out[M_ROWS + id] = sd * (1.0f / 768.0f);
    }
}

// ---------------------------------------------------------------------------
// GEMM (m97 structure + L2 swizzle): C = A(MxK) @ Bt(NxK)^T + bias.
// 128x128x32 tile, global_load_lds width=16 staging, 1D grid with GROUP_M=16
// swizzle (16 M-tiles x all N-tiles per group stay L2-resident).
// ldc decouples output stride from N (fused multi-segment outputs).
// EPI: 0 -> C = x ; 1 -> C = res - gelu(x) ; 2 -> C = res + gelu(x)
// ---------------------------------------------------------------------------
template<int EPI>
__global__ __launch_bounds__(256)
void gemm_bt(const bf16* __restrict__ A, const bf16* __restrict__ Bt,
             const bf16* __restrict__ bias, const bf16* __restrict__ res,
             bf16* __restrict__ C, int ldc, int K, int mTiles, int nTiles)
{
    constexpr int BM = 128, BK = 32;
    __shared__ alignas(16) bf16 sA[BM * BK];
    __shared__ alignas(16) bf16 sB[BM * BK];
    const int tid  = threadIdx.x;
    const int lane = tid & 63, wave = tid >> 6;
    const int wm   = wave >> 1, wn = wave & 1;
    const int quad = lane >> 4, l16 = lane & 15;

    // GROUP_M swizzle
    const int GM = 16;
    int pid   = blockIdx.x;
    int group = GM * nTiles;
    int gid   = pid / group;
    int rem   = pid - gid * group;
    int first = gid * GM;
    int gm    = (mTiles - first < GM) ? (mTiles - first) : GM;
    int bm    = first + rem % gm;
    int bn    = rem / gm;

    const long m0 = (long)bm * BM;
    const long n0 = (long)bn * BM;

    f32x4 acc[4][4] = {};

    for (int kt = 0; kt < K; kt += BK) {
        if (kt) __syncthreads();
        #pragma unroll
        for (int c = 0; c < 2; ++c) {
            int ci = (wave * 2 + c) * 64 + lane;
            int r  = ci >> 2, kc = ci & 3;
            const bf16* ga = A  + (m0 + r) * K + kt + kc * 8;
            const bf16* gb = Bt + (n0 + r) * K + kt + kc * 8;
            bf16* la = sA + (wave * 2 + c) * 512;
            bf16* lb = sB + (wave * 2 + c) * 512;
            GLOAD_LDS16(ga, la);
            GLOAD_LDS16(gb, lb);
        }
        __syncthreads();

        bf16x8 af[4], bfr[4];
        #pragma unroll
        for (int mi = 0; mi < 4; ++mi)
            af[mi] = *(const bf16x8*)(sA + (wm * 64 + mi * 16 + l16) * BK + quad * 8);
        #pragma unroll
        for (int ni = 0; ni < 4; ++ni)
            bfr[ni] = *(const bf16x8*)(sB + (wn * 64 + ni * 16 + l16) * BK + quad * 8);
        #pragma unroll
        for (int mi = 0; mi < 4; ++mi)
            #pragma unroll
            for (int ni = 0; ni < 4; ++ni)
                acc[mi][ni] = __builtin_amdgcn_mfma_f32_16x16x32_bf16(af[mi], bfr[ni], acc[mi][ni], 0, 0, 0);
    }

    // Epilogue. D layout: col = lane&15, row = quad*4 + r
    #pragma unroll
    for (int mi = 0; mi < 4; ++mi) {
        #pragma unroll
        for (int ni = 0; ni < 4; ++ni) {
            int mg = (int)m0 + wm * 64 + mi * 16 + quad * 4;
            int ng = (int)n0 + wn * 64 + ni * 16 + l16;
            float bn_ = bf2f(bias[ng]);
            #pragma unroll
            for (int r = 0; r < 4; ++r) {
                float x = acc[mi][ni][r] + bn_;
                long off = (long)(mg + r) * ldc + ng;
                if (EPI == 0)      C[off] = f2bf(x);
                else if (EPI == 1) C[off] = f2bf(bf2f(res[off]) - gelu_exact(x));
                else               C[off] = f2bf(bf2f(res[off]) + gelu_exact(x));
            }
        }
    }
}

// ---------------------------------------------------------------------------
// MFMA attention, stride-parameterized. One block per (head h, instance bj).
// St = K·Q^T, in-register softmax, O^T = V^T·P^T via ds_bpermute fragments.
// ---------------------------------------------------------------------------
#define KSTR 72
#define VSTR 264

__global__ __launch_bounds__(256)
void attn_mfma(const bf16* __restrict__ Q, int ldq,
               const bf16* __restrict__ KV, int ldkv,
               bf16* __restrict__ O)
{
    const int h  = blockIdx.x;   // 12
    const int bj = blockIdx.y;   // 128
    __shared__ alignas(16) bf16 Ks[208 * KSTR];
    __shared__ alignas(16) bf16 Vt[64 * VSTR];
    const int tid = threadIdx.x, lane = tid & 63, wave = tid >> 6;
    const int quad = lane >> 4, l16 = lane & 15;

    const bf16* qg = Q  + (long)bj * S196 * ldq  + h * 64;
    const bf16* kg = KV + (long)bj * S196 * ldkv + h * 64;
    const bf16* vg = kg + CC;   // v block sits 768 past k within kv row

    for (int i = tid; i < 208 * 8; i += 256) {
        int r = i >> 3, c8 = (i & 7) * 8;
        bf16x8 v = {};
        if (r < S196) v = *(const bf16x8*)(kg + (long)r * ldkv + c8);
        *(bf16x8*)(Ks + r * KSTR + c8) = v;
    }
    for (int i = tid; i < 256 * 8; i += 256) {
        int g   = i >> 6;
        int c8  = (g & 7) * 8;
        int tok = (g >> 3) * 64 + (i & 63);
        bf16x8 v = {};
        if (tok < S196) v = *(const bf16x8*)(vg + (long)tok * ldkv + c8);
        #pragma unroll
        for (int j = 0; j < 8; ++j)
            Vt[(c8 + j) * VSTR + tok] = v[j];
    }
    __syncthreads();

    for (int qt = wave; qt < 13; qt += 4) {
        int qrow = qt * 16 + l16; if (qrow > 195) qrow = 195;
        const bf16* qrp = qg + (long)qrow * ldq + quad * 8;
        bf16x8 qf0 = *(const bf16x8*)(qrp);
        bf16x8 qf1 = *(const bf16x8*)(qrp + 32);

        f32x4 st[13];
        #pragma unroll
        for (int rt = 0; rt < 13; ++rt) st[rt] = (f32x4){0.f, 0.f, 0.f, 0.f};
        #pragma unroll
        for (int rt = 0; rt < 13; ++rt) {
            const bf16* kb = Ks + (rt * 16 + l16) * KSTR + quad * 8;
            bf16x8 kf0 = *(const bf16x8*)(kb);
            bf16x8 kf1 = *(const bf16x8*)(kb + 32);
            st[rt] = __builtin_amdgcn_mfma_f32_16x16x32_bf16(kf0, qf0, st[rt], 0, 0, 0);
            st[rt] = __builtin_amdgcn_mfma_f32_16x16x32_bf16(kf1, qf1, st[rt], 0, 0, 0);
        }

        const float SC = 0.125f;
        #pragma unroll
        for (int rt = 0; rt < 13; ++rt) {
            st[rt][0] *= SC; st[rt][1] *= SC; st[rt][2] *= SC; st[rt][3] *= SC;
        }
        if (quad != 0)
            st[12] = (f32x4){-1e30f, -1e30f, -1e30f, -1e30f};

        float m = -1e30f;
        #pragma unroll
        for (int rt = 0; rt < 13; ++rt)
            m = fmaxf(m, fmaxf(fmaxf(st[rt][0], st[rt][1]), fmaxf(st[rt][2], st[rt][3])));
        m = fmaxf(m, __shfl_xor(m, 16, 64));
        m = fmaxf(m, __shfl_xor(m, 32, 64));
        float sum = 0.f;
        #pragma unroll
        for (int rt = 0; rt < 13; ++rt) {
            st[rt][0] = __expf(st[rt][0] - m);
            st[rt][1] = __expf(st[rt][1] - m);
            st[rt][2] = __expf(st[rt][2] - m);
            st[rt][3] = __expf(st[rt][3] - m);
            sum += st[rt][0] + st[rt][1] + st[rt][2] + st[rt][3];
        }
        sum += __shfl_xor(sum, 16, 64);
        sum += __shfl_xor(sum, 32, 64);
        float inv = 1.0f / sum;

        unsigned int pk[13][2];
        #pragma unroll
        for (int rt = 0; rt < 13; ++rt) {
            pk[rt][0] = packbf(st[rt][0] * inv, st[rt][1] * inv);
            pk[rt][1] = packbf(st[rt][2] * inv, st[rt][3] * inv);
        }

        f32x4 ot[4];
        #pragma unroll
        for (int dt = 0; dt < 4; ++dt) ot[dt] = (f32x4){0.f, 0.f, 0.f, 0.f};
        #pragma unroll
        for (int c = 0; c < 7; ++c) {
            u32x4 fp;
            #pragma unroll
            for (int jp = 0; jp < 4; ++jp) {
                int jh = jp >> 1, rp = jp & 1;
                int srcb = ((((quad & 1) << 1) + jh) << 6) | (l16 << 2);
                int a = __builtin_amdgcn_ds_bpermute(srcb, (int)pk[2 * c][rp]);
                int b = (c < 6) ? __builtin_amdgcn_ds_bpermute(srcb, (int)pk[2 * c + 1][rp]) : 0;
                fp[jp] = (quad >> 1) ? (unsigned int)b : (unsigned int)a;
            }
            bf16x8 pB = __builtin_bit_cast(bf16x8, fp);
            #pragma unroll
            for (int dt = 0; dt < 4; ++dt) {
                bf16x8 vf = *(const bf16x8*)(Vt + (dt * 16 + l16) * VSTR + c * 32 + quad * 8);
                ot[dt] = __builtin_amdgcn_mfma_f32_16x16x32_bf16(vf, pB, ot[dt], 0, 0, 0);
            }
        }

        int token = qt * 16 + l16;
        if (token < S196) {
            bf16* op = O + ((long)bj * S196 + token) * CC + h * 64 + quad * 4;
            #pragma unroll
            for (int dt = 0; dt < 4; ++dt) {
                bf16x4 v;
                v[0] = f2bf(ot[dt][0]); v[1] = f2bf(ot[dt][1]);
                v[2] = f2bf(ot[dt][2]); v[3] = f2bf(ot[dt][3]);
                *(bf16x4*)(op + dt * 16) = v;
            }
        }
    }
}

// ---------------------------------------------------------------------------
extern "C" void kernel_launch(void* const* d_in, const int* in_sizes, int n_in,
                              void* d_out, int out_size, void* d_ws, size_t ws_size,
                              hipStream_t stream)
{
    const float* x_in  = (const float*)d_in[0];
    const float* Wq_d  = (const float*)d_in[1];
    const float* bq_d  = (const float*)d_in[2];
    const float* Wkv_a = (const float*)d_in[3];
    const float* bkv_a = (const float*)d_in[4];
    const float* Wq_a  = (const float*)d_in[5];
    const float* bq_a  = (const float*)d_in[6];
    const float* Wkv_d = (const float*)d_in[7];
    const float* bkv_d = (const float*)d_in[8];
    const float* Wp_d  = (const float*)d_in[9];
    const float* bp_d  = (const float*)d_in[10];
    const float* Wp_a  = (const float*)d_in[11];
    const float* bp_a  = (const float*)d_in[12];
    float* out = (float*)d_out;

    char* w = (char*)d_ws;
    auto alloc = [&](size_t elems) {
        bf16* p = (bf16*)w;
        w += ((elems * 2 + 255) / 256) * 256;
        return p;
    };
    bf16* biasAll = alloc(6144);
    bf16* WtQd  = alloc((size_t)768 * 768);
    bf16* WtACat= alloc((size_t)2304 * 768);   // [Wkv_a^T ; Wq_a^T]
    bf16* WtKd  = alloc((size_t)1536 * 768);
    bf16* WtPd  = alloc((size_t)768 * 768);
    bf16* WtPa  = alloc((size_t)768 * 768);
    bf16* xa    = alloc((size_t)M_ROWS * 768);
    bf16* xd    = alloc((size_t)M_ROWS * 768);
    bf16* Qb    = alloc((size_t)M_ROWS * 768);
    bf16* QKVa  = alloc((size_t)M_ROWS * 2304); // cols 0..1535 kv, 1536..2303 q_a
    bf16* Ob    = alloc((size_t)M_ROWS * 768);
    float* pool0 = (float*)w; w += ((size_t)M_ROWS * 4 + 255) / 256 * 256;

    dim3 blk(256);
    transpose_w<<<dim3(24, 24), blk, 0, stream>>>(Wq_d,  WtQd, 768, 768);
    transpose_w<<<dim3(24, 48), blk, 0, stream>>>(Wkv_a, WtACat, 768, 1536);
    transpose_w<<<dim3(24, 24), blk, 0, stream>>>(Wq_a,  WtACat + (size_t)1536 * 768, 768, 768);
    transpose_w<<<dim3(24, 48), blk, 0, stream>>>(Wkv_d, WtKd, 768, 1536);
    transpose_w<<<dim3(24, 24), blk, 0, stream>>>(Wp_d,  WtPd, 768, 768);
    transpose_w<<<dim3(24, 24), blk, 0, stream>>>(Wp_a,  WtPa, 768, 768);
    conv_bias<<<dim3(6), blk, 0, stream>>>(bq_d, bkv_a, bq_a, bkv_d, bp_d, bp_a, biasAll);

    long total_chunks = (long)BATCH * 16 * S196 * 96;
    int  rblocks = (int)((total_chunks + 255) / 256);
    reorder_split<<<rblocks, blk, 0, stream>>>(x_in, xa, xd);
    pool_ad<<<M_ROWS / 4, blk, 0, stream>>>(xa, xd, pool0);

    const bf16* Bq_d   = biasAll;
    const bf16* Bkva_qa= biasAll + 768;   // 2304-wide: bkv_a | bq_a
    const bf16* Bkv_d  = biasAll + 3072;
    const bf16* Bp_d   = biasAll + 4608;
    const bf16* Bp_a   = biasAll + 5376;

    // mTiles = 196; nTiles: 6 (768), 12 (1536), 18 (2304)
    // Phase 1: Qb = xd@Wq_d ; QKVa = xa@[Wkv_a|Wq_a]
    gemm_bt<0><<<196 * 6,  blk, 0, stream>>>(xd, WtQd,  Bq_d,    nullptr, Qb,   768,  768, 196, 6);
    gemm_bt<0><<<196 * 18, blk, 0, stream>>>(xa, WtACat, Bkva_qa, nullptr, QKVa, 2304, 768, 196, 18);
    attn_mfma<<<dim3(12, 128), blk, 0, stream>>>(Qb, 768, QKVa, 2304, Ob);
    gemm_bt<1><<<196 * 6,  blk, 0, stream>>>(Ob, WtPd, Bp_d, xd, xd, 768, 768, 196, 6);

    // Phase 2: kv_d overwrites QKVa cols 0..1535 (kv_a is dead after attn1)
    gemm_bt<0><<<196 * 12, blk, 0, stream>>>(xd, WtKd, Bkv_d, nullptr, QKVa, 2304, 768, 196, 12);
    attn_mfma<<<dim3(12, 128), blk, 0, stream>>>(QKVa + 1536, 2304, QKVa, 2304, Ob);
    gemm_bt<2><<<196 * 6,  blk, 0, stream>>>(Ob, WtPa, Bp_a, xa, xa, 768, 768, 196, 6);

    out_final<<<M_ROWS / 4, blk, 0, stream>>>(xa, xd, pool0, out);
}